// Round 3
// baseline (3250.743 us; speedup 1.0000x reference)
//
#include <hip/hip_runtime.h>
#include <hip/hip_bf16.h>

#define DEVINL __device__ __forceinline__

constexpr int N_SITES = 500000;
constexpr int C1 = 128;
constexpr int CH = 64;
constexpr int C2 = 128;
constexpr float BN_EPS = 1e-5f;

// bf16 helpers (bf16 value lives in high 16 bits of an f32)
DEVINL float bflo(unsigned u) { return __uint_as_float(u << 16); }
DEVINL float bfhi(unsigned u) { return __uint_as_float(u & 0xffff0000u); }
DEVINL float bf2f(unsigned short s) { return __uint_as_float(((unsigned)s) << 16); }
DEVINL unsigned short f2bf(float f) {
  unsigned u = __float_as_uint(f);
  unsigned r = (u + 0x7fffu + ((u >> 16) & 1u)) >> 16;  // RNE
  return (unsigned short)r;
}
DEVINL float silu_f(float x) { return x / (1.0f + __expf(-x)); }

// Read scalar float from a buffer that is either fp32 or bf16.
template<bool F32>
DEVINL float rdf(const void* p, long i) {
  if constexpr (F32) return ((const float*)p)[i];
  else return bf2f(((const unsigned short*)p)[i]);
}
// Load 8 consecutive float elements as packed bf16 pairs (uint4).
template<bool F32>
DEVINL uint4 load8(const void* base, long elem_ofs) {
  if constexpr (!F32) {
    return *(const uint4*)((const unsigned short*)base + elem_ofs);
  } else {
    const float4* f = (const float4*)((const float*)base + elem_ofs);
    float4 a = f[0], b = f[1];
    uint4 r;
    r.x = (unsigned)f2bf(a.x) | ((unsigned)f2bf(a.y) << 16);
    r.y = (unsigned)f2bf(a.z) | ((unsigned)f2bf(a.w) << 16);
    r.z = (unsigned)f2bf(b.x) | ((unsigned)f2bf(b.y) << 16);
    r.w = (unsigned)f2bf(b.z) | ((unsigned)f2bf(b.w) << 16);
    return r;
  }
}

// Probe: is this float buffer fp32?  For packed bf16, the low 16 bits of each
// word are a bf16 value whose exponent field lies in [90,134] for any sane
// data scale; for fp32 the low 16 bits are uniform mantissa bits (~18% hit).
DEVINL bool probe_f32(const void* buf) {
  unsigned w = ((const unsigned*)buf)[threadIdx.x & 63];
  unsigned e = (w >> 7) & 0xFFu;
  bool bf_like = (e >= 90u && e <= 134u) || ((w & 0xFFFFu) == 0u);
  return __popcll(__ballot(bf_like)) < 48;
}
// Probe: is the index buffer int64?  Values are in [0, 500000] >= 0, so the
// high words of int64 entries are all zero; int32 odd entries are real indices.
DEVINL bool probe_i64(const int* nbr) {
  int v = nbr[2 * (threadIdx.x & 63) + 1];
  return __popcll(__ballot(v == 0)) == 64;
}
template<bool I64>
DEVINL int rd_idx(const int* nbr, long ofs) {
  if constexpr (I64) return nbr[2 * ofs];
  else return nbr[ofs];
}

// ---------------------------------------------------------------------------
// K1: h = silu(bn1(features @ W1)), h stored bf16.  One wave per site.
// ---------------------------------------------------------------------------
template<bool F32>
DEVINL void cv1_body(const void* feat, const void* W1,
                     const void* g1, const void* b1, const void* m1, const void* v1,
                     unsigned short* __restrict__ h, unsigned (*lw1)[65])
{
  const int tid = threadIdx.x;
  for (int idx = tid; idx < CH * 64; idx += 256) {
    int c = idx >> 6, j2 = idx & 63;
    unsigned lo = f2bf(rdf<F32>(W1, (long)(2 * j2) * CH + c));
    unsigned hi = f2bf(rdf<F32>(W1, (long)(2 * j2 + 1) * CH + c));
    lw1[c][j2] = lo | (hi << 16);
  }
  const int w = tid >> 6, c = tid & 63;
  const float sc = rdf<F32>(g1, c) * rsqrtf(rdf<F32>(v1, c) + BN_EPS);
  const float sh = rdf<F32>(b1, c) - rdf<F32>(m1, c) * sc;
  __syncthreads();

  const int stride = gridDim.x * 4;
  for (int site = blockIdx.x * 4 + w; site < N_SITES; site += stride) {
    float acc = 0.f;
#pragma unroll
    for (int q = 0; q < 16; ++q) {
      uint4 fq = load8<F32>(feat, (long)site * C1 + q * 8);
      unsigned wv;
      wv = lw1[c][q * 4 + 0]; acc += bflo(fq.x) * bflo(wv) + bfhi(fq.x) * bfhi(wv);
      wv = lw1[c][q * 4 + 1]; acc += bflo(fq.y) * bflo(wv) + bfhi(fq.y) * bfhi(wv);
      wv = lw1[c][q * 4 + 2]; acc += bflo(fq.z) * bflo(wv) + bfhi(fq.z) * bfhi(wv);
      wv = lw1[c][q * 4 + 3]; acc += bflo(fq.w) * bflo(wv) + bfhi(fq.w) * bfhi(wv);
    }
    h[(size_t)site * CH + c] = f2bf(silu_f(acc * sc + sh));
  }
}

__global__ __launch_bounds__(256, 4) void k_cv1(
    const void* feat, const void* W1,
    const void* g1, const void* b1, const void* m1, const void* v1,
    unsigned short* __restrict__ h)
{
  __shared__ unsigned lw1[CH][65];
  if (probe_f32(feat)) cv1_body<true>(feat, W1, g1, b1, m1, v1, h, lw1);
  else                 cv1_body<false>(feat, W1, g1, b1, m1, v1, h, lw1);
}

// ---------------------------------------------------------------------------
// K2a: p = sum_{k=0..4} gather(h, nbr[k]) @ W2[k]   (partial cv2, bf16 out)
// ---------------------------------------------------------------------------
constexpr int K_A = 5;
template<bool F32, bool I64>
DEVINL void cv2a_body(const unsigned short* __restrict__ h, const int* __restrict__ nbr,
                      const void* W2, unsigned short* __restrict__ p,
                      unsigned (*lw2)[CH][33])
{
  const int tid = threadIdx.x;
  for (int idx = tid; idx < K_A * CH * 32; idx += 256) {
    int k = idx / (CH * 32);
    int r = idx % (CH * 32);
    int c = r >> 5, j2 = r & 31;
    unsigned lo = f2bf(rdf<F32>(W2, (long)((k * CH) + 2 * j2) * CH + c));
    unsigned hi = f2bf(rdf<F32>(W2, (long)((k * CH) + 2 * j2 + 1) * CH + c));
    lw2[k][c][j2] = lo | (hi << 16);
  }
  const int w = tid >> 6, c = tid & 63;
  __syncthreads();

  const int stride = gridDim.x * 4;
  for (int site = blockIdx.x * 4 + w; site < N_SITES; site += stride) {
    float acc = 0.f;
#pragma unroll
    for (int k = 0; k < K_A; ++k) {
      int row = rd_idx<I64>(nbr, (long)k * N_SITES + site);   // wave-uniform
      if (row == N_SITES) continue;                           // inactive
      const uint4* hr = (const uint4*)(h + (size_t)row * CH);
#pragma unroll
      for (int q = 0; q < 8; ++q) {
        uint4 hq = hr[q];
        unsigned wv;
        wv = lw2[k][c][q * 4 + 0]; acc += bflo(hq.x) * bflo(wv) + bfhi(hq.x) * bfhi(wv);
        wv = lw2[k][c][q * 4 + 1]; acc += bflo(hq.y) * bflo(wv) + bfhi(hq.y) * bfhi(wv);
        wv = lw2[k][c][q * 4 + 2]; acc += bflo(hq.z) * bflo(wv) + bfhi(hq.z) * bfhi(wv);
        wv = lw2[k][c][q * 4 + 3]; acc += bflo(hq.w) * bflo(wv) + bfhi(hq.w) * bfhi(wv);
      }
    }
    p[(size_t)site * CH + c] = f2bf(acc);
  }
}

__global__ __launch_bounds__(256, 4) void k_cv2a(
    const unsigned short* __restrict__ h, const int* __restrict__ nbr,
    const void* W2, unsigned short* __restrict__ p)
{
  __shared__ unsigned lw2[K_A][CH][33];
  bool f32 = probe_f32(W2);
  bool i64 = probe_i64(nbr);
  if (f32) { if (i64) cv2a_body<true , true >(h, nbr, W2, p, lw2);
             else     cv2a_body<true , false>(h, nbr, W2, p, lw2); }
  else     { if (i64) cv2a_body<false, true >(h, nbr, W2, p, lw2);
             else     cv2a_body<false, false>(h, nbr, W2, p, lw2); }
}

// ---------------------------------------------------------------------------
// K2b: acc = p + sum_{k=5..8} gather(h, nbr[k]) @ W2[k];
//      t = silu(bn2(acc)); o = bn3(t @ W3); out = silu(o + features)
// ---------------------------------------------------------------------------
template<bool F32, bool I64>
DEVINL void cv2b_body(const unsigned short* __restrict__ h, const int* __restrict__ nbr,
                      const void* W2, const void* W3,
                      const unsigned short* __restrict__ p, const void* feat,
                      const void* g2, const void* b2, const void* m2, const void* v2,
                      const void* g3, const void* b3, const void* m3, const void* v3,
                      void* out, unsigned (*lw2)[CH][33], unsigned (*lw3)[33],
                      float (*lt)[CH])
{
  const int tid = threadIdx.x;
  for (int idx = tid; idx < 4 * CH * 32; idx += 256) {
    int k = idx / 2048;
    int r = idx & 2047;
    int c = r >> 5, j2 = r & 31;
    unsigned lo = f2bf(rdf<F32>(W2, (long)(((k + 5) * CH) + 2 * j2) * CH + c));
    unsigned hi = f2bf(rdf<F32>(W2, (long)(((k + 5) * CH) + 2 * j2 + 1) * CH + c));
    lw2[k][c][j2] = lo | (hi << 16);
  }
  for (int idx = tid; idx < C2 * 32; idx += 256) {
    int d = idx >> 5, j2 = idx & 31;
    unsigned lo = f2bf(rdf<F32>(W3, (long)(2 * j2) * C2 + d));
    unsigned hi = f2bf(rdf<F32>(W3, (long)(2 * j2 + 1) * C2 + d));
    lw3[d][j2] = lo | (hi << 16);
  }
  const int w = tid >> 6, c = tid & 63;
  const float s2 = rdf<F32>(g2, c) * rsqrtf(rdf<F32>(v2, c) + BN_EPS);
  const float t2 = rdf<F32>(b2, c) - rdf<F32>(m2, c) * s2;
  const float s3a = rdf<F32>(g3, c) * rsqrtf(rdf<F32>(v3, c) + BN_EPS);
  const float t3a = rdf<F32>(b3, c) - rdf<F32>(m3, c) * s3a;
  const float s3b = rdf<F32>(g3, c + 64) * rsqrtf(rdf<F32>(v3, c + 64) + BN_EPS);
  const float t3b = rdf<F32>(b3, c + 64) - rdf<F32>(m3, c + 64) * s3b;
  __syncthreads();

  const int stride = gridDim.x * 4;
  for (int site = blockIdx.x * 4 + w; site < N_SITES; site += stride) {
    float acc = bf2f(p[(size_t)site * CH + c]);
#pragma unroll
    for (int k = 0; k < 4; ++k) {
      int row = rd_idx<I64>(nbr, (long)(k + 5) * N_SITES + site);  // wave-uniform
      if (row == N_SITES) continue;                                // inactive
      const uint4* hr = (const uint4*)(h + (size_t)row * CH);
#pragma unroll
      for (int q = 0; q < 8; ++q) {
        uint4 hq = hr[q];
        unsigned wv;
        wv = lw2[k][c][q * 4 + 0]; acc += bflo(hq.x) * bflo(wv) + bfhi(hq.x) * bfhi(wv);
        wv = lw2[k][c][q * 4 + 1]; acc += bflo(hq.y) * bflo(wv) + bfhi(hq.y) * bfhi(wv);
        wv = lw2[k][c][q * 4 + 2]; acc += bflo(hq.z) * bflo(wv) + bfhi(hq.z) * bfhi(wv);
        wv = lw2[k][c][q * 4 + 3]; acc += bflo(hq.w) * bflo(wv) + bfhi(hq.w) * bfhi(wv);
      }
    }
    float t = silu_f(acc * s2 + t2);
    lt[w][c] = t;   // same-wave write->read exchange (in-order DS, may-alias)
    __builtin_amdgcn_wave_barrier();
    float o1 = 0.f, o2 = 0.f;
#pragma unroll
    for (int j2 = 0; j2 < 32; ++j2) {
      float2 tp = *(const float2*)&lt[w][2 * j2];
      unsigned wa = lw3[c][j2];        // d = c
      unsigned wb = lw3[c + 64][j2];   // d = c + 64
      o1 += tp.x * bflo(wa) + tp.y * bfhi(wa);
      o2 += tp.x * bflo(wb) + tp.y * bfhi(wb);
    }
    __builtin_amdgcn_wave_barrier();
    o1 = o1 * s3a + t3a;
    o2 = o2 * s3b + t3b;
    float f1 = rdf<F32>(feat, (long)site * C1 + c);
    float f2v = rdf<F32>(feat, (long)site * C1 + 64 + c);
    float r1 = silu_f(o1 + f1), r2 = silu_f(o2 + f2v);
    if constexpr (F32) {
      ((float*)out)[(size_t)site * C2 + c] = r1;
      ((float*)out)[(size_t)site * C2 + 64 + c] = r2;
    } else {
      ((unsigned short*)out)[(size_t)site * C2 + c] = f2bf(r1);
      ((unsigned short*)out)[(size_t)site * C2 + 64 + c] = f2bf(r2);
    }
  }
}

__global__ __launch_bounds__(256, 4) void k_cv2b(
    const unsigned short* __restrict__ h, const int* __restrict__ nbr,
    const void* W2, const void* W3,
    const unsigned short* __restrict__ p, const void* feat,
    const void* g2, const void* b2, const void* m2, const void* v2,
    const void* g3, const void* b3, const void* m3, const void* v3,
    void* out)
{
  __shared__ unsigned lw2[4][CH][33];
  __shared__ unsigned lw3[C2][33];
  __shared__ float lt[4][CH];
  bool f32 = probe_f32(feat);
  bool i64 = probe_i64(nbr);
  if (f32) { if (i64) cv2b_body<true , true >(h, nbr, W2, W3, p, feat, g2, b2, m2, v2, g3, b3, m3, v3, out, lw2, lw3, lt);
             else     cv2b_body<true , false>(h, nbr, W2, W3, p, feat, g2, b2, m2, v2, g3, b3, m3, v3, out, lw2, lw3, lt); }
  else     { if (i64) cv2b_body<false, true >(h, nbr, W2, W3, p, feat, g2, b2, m2, v2, g3, b3, m3, v3, out, lw2, lw3, lt);
             else     cv2b_body<false, false>(h, nbr, W2, W3, p, feat, g2, b2, m2, v2, g3, b3, m3, v3, out, lw2, lw3, lt); }
}

// ---------------------------------------------------------------------------
extern "C" void kernel_launch(void* const* d_in, const int* in_sizes, int n_in,
                              void* d_out, int out_size, void* d_ws, size_t ws_size,
                              hipStream_t stream)
{
  (void)out_size; (void)ws_size;
  // Map inputs by position, verified/remapped via the unique size signature.
  // dict order: feat(64e6) nbr(4.5e6) W1 W2 W3 g1 b1 m1 v1 g2 b2 m2 v2 g3 b3 m3 v3
  // alpha order: W1 W2 W3 b1 b2 b3 features g1 g2 g3 m1 m2 m3 nbr_idx v1 v2 v3
  int mp[17];
  for (int i = 0; i < 17; ++i) mp[i] = i;  // default: dict order
  if (n_in == 17 && in_sizes[0] != 64000000 &&
      in_sizes[6] == 64000000 && in_sizes[13] == 4500000) {
    // alphabetical layout detected; remap to dict order
    const int amap[17] = {6, 13, 0, 1, 2, 7, 3, 10, 14, 8, 4, 11, 15, 9, 5, 12, 16};
    for (int i = 0; i < 17; ++i) mp[i] = amap[i];
  }
  const void* feat = d_in[mp[0]];
  const int*  nbr  = (const int*)d_in[mp[1]];
  const void* W1 = d_in[mp[2]];
  const void* W2 = d_in[mp[3]];
  const void* W3 = d_in[mp[4]];
  const void* g1 = d_in[mp[5]],  *b1 = d_in[mp[6]],  *m1 = d_in[mp[7]],  *v1 = d_in[mp[8]];
  const void* g2 = d_in[mp[9]],  *b2 = d_in[mp[10]], *m2 = d_in[mp[11]], *v2 = d_in[mp[12]];
  const void* g3 = d_in[mp[13]], *b3 = d_in[mp[14]], *m3 = d_in[mp[15]], *v3 = d_in[mp[16]];

  // workspace: h = N*64 bf16 (64,000,000 B), p = N*64 bf16 (64,000,000 B)
  unsigned short* h = (unsigned short*)d_ws;
  unsigned short* p = (unsigned short*)((char*)d_ws + (size_t)N_SITES * CH * 2);

  const int blocks = 1024;
  k_cv1<<<blocks, 256, 0, stream>>>(feat, W1, g1, b1, m1, v1, h);
  k_cv2a<<<blocks, 256, 0, stream>>>(h, nbr, W2, p);
  k_cv2b<<<blocks, 256, 0, stream>>>(h, nbr, W2, W3, p, feat,
                                     g2, b2, m2, v2, g3, b3, m3, v3, (void*)d_out);
}